// Round 13
// baseline (1390.391 us; speedup 1.0000x reference)
//
#include <hip/hip_runtime.h>
#include <hip/hip_fp16.h>

#define B_ 128
#define T_ 64
#define I_ 128
#define H_ 256
#define UF 6
#define EPSF 1e-8f

typedef _Float16 f16x2 __attribute__((ext_vector_type(2)));
union H2U { __half2 h; f16x2 v; unsigned u; };

static __device__ __forceinline__ float rcpf(float x) { return __builtin_amdgcn_rcpf(x); }
static __device__ __forceinline__ unsigned f2h(float f) { return (unsigned)__half_as_ushort(__float2half_rn(f)); }

// packed-fp16 dual gate: 2 sigmoids + f32 dot-accumulate into NM/DN (R7-proven)
#define GATE2(VW, AK, BK, WK, NM, DN) {                        \
    H2U v2_; v2_.u = (VW);                                     \
    H2U av_; av_.u = (AK);                                     \
    H2U bv_; bv_.u = (BK);                                     \
    __half2 z_ = __hfma2(av_.h, v2_.h, bv_.h);                 \
    __half2 e_ = h2exp2(z_);                                   \
    __half2 s_ = __hadd2(e_, __float2half2_rn(1.0f));          \
    H2U rv_; rv_.h = h2rcp(s_);                                \
    H2U ws_; ws_.u = (WK);                                     \
    H2U wa_; wa_.u = ws_.u & 0x7fff7fffu;                      \
    NM = __builtin_amdgcn_fdot2(ws_.v, rv_.v, NM, false);      \
    DN = __builtin_amdgcn_fdot2(wa_.v, rv_.v, DN, false);      \
}

// ---------------- K0: pack params (A = -sig*L2E, B = sig*mu*L2E, W = w*erev).
// Internal AB: bank-swizzled [jh][P][jcol] uint2, jcol = j ^ 2*((P>>3)&7).
// Internal W:  [P][jg] packed pairs. Sensing: SAB [p][jg] uint2, SW [p][jg].
// Zero the exchange tags (both buffers) every launch.
__global__ __launch_bounds__(256) void pack_params(
    const float* __restrict__ smu, const float* __restrict__ ssig,
    const float* __restrict__ sw,  const float* __restrict__ serev,
    const float* __restrict__ imu, const float* __restrict__ isig,
    const float* __restrict__ iw,  const float* __restrict__ ierev,
    uint2* __restrict__ ABg, unsigned* __restrict__ Wg,
    uint2* __restrict__ SABg, unsigned* __restrict__ SWg,
    unsigned* __restrict__ Vg4)
{
    const float K = 1.4426950408889634f;
    int idx = blockIdx.x * 256 + threadIdx.x;     // [0, 32768)
    {   // internal AB, swizzled columns
        int jh = idx >> 14, rest = idx & 16383;
        int P = rest >> 7, jcol = rest & 127;
        int j = jcol ^ (((P >> 3) & 7) << 1);
        int jg = (jh << 7) + j;
        int i0 = 2 * P, i1 = i0 + 1;
        unsigned a0 = f2h(-isig[i0 * H_ + jg] * K);
        unsigned a1 = f2h(-isig[i1 * H_ + jg] * K);
        unsigned b0 = f2h(isig[i0 * H_ + jg] * imu[i0 * H_ + jg] * K);
        unsigned b1 = f2h(isig[i1 * H_ + jg] * imu[i1 * H_ + jg] * K);
        ABg[idx] = make_uint2(a0 | (a1 << 16), b0 | (b1 << 16));
    }
    {   // internal W [P][jg]
        int P = idx >> 8, jg = idx & 255;
        int i0 = 2 * P, i1 = i0 + 1;
        unsigned w0 = f2h(iw[i0 * H_ + jg] * ierev[i0 * H_ + jg]);
        unsigned w1 = f2h(iw[i1 * H_ + jg] * ierev[i1 * H_ + jg]);
        Wg[idx] = w0 | (w1 << 16);
    }
    if (idx < 64 * H_) {   // sensing [p][jg]
        int p = idx >> 8, jg = idx & 255;
        int i0 = 2 * p, i1 = i0 + 1;
        unsigned a0 = f2h(-ssig[i0 * H_ + jg] * K);
        unsigned a1 = f2h(-ssig[i1 * H_ + jg] * K);
        unsigned b0 = f2h(ssig[i0 * H_ + jg] * smu[i0 * H_ + jg] * K);
        unsigned b1 = f2h(ssig[i1 * H_ + jg] * smu[i1 * H_ + jg] * K);
        SABg[idx] = make_uint2(a0 | (a1 << 16), b0 | (b1 << 16));
        unsigned w0 = f2h(sw[i0 * H_ + jg] * serev[i0 * H_ + jg]);
        unsigned w1 = f2h(sw[i1 * H_ + jg] * serev[i1 * H_ + jg]);
        SWg[idx] = w0 | (w1 << 16);
    }
    Vg4[idx] = 0u;
    Vg4[idx + 32768] = 0u;
}

// ---------------- K1: recurrent LTC (R7 base + balanced poll + pipelined sensing).
// 2 blocks per batch (j-half each), 1 block/CU (131 KB LDS), all 256 co-resident.
// Lane map tid = j*8 + c; 8 partials per neuron reduce via shfl_xor in-wave.
// Internal A,B in LDS (XOR-swizzled); internal W register-cached; V exchanged
// via self-tagged relaxed agent atomics, double-buffered by unfold parity.
// Poll: lanes 0-7 of EVERY wave pull 1 tagged word (1 VMEM/wave, issued before
// phase A, spin after) -> no 2-wave straggler at barrier-a. Sensing for t+1 is
// pipelined into t's unfolds (1,1,1,1,2,2 GATE2s, params prefetched at unfold
// top under phase A; xs2 double-buffered, visibility via barrier-a).
__global__ __launch_bounds__(1024)
__attribute__((amdgpu_waves_per_eu(4, 4)))
void ltc_rec(
    const float* __restrict__ x, const float* __restrict__ in_w, const float* __restrict__ in_b,
    const uint2* __restrict__ ABg, const unsigned* __restrict__ Wg,
    const uint2* __restrict__ SABg, const unsigned* __restrict__ SWg,
    const float* __restrict__ vleak, const float* __restrict__ gleak, const float* __restrict__ cm,
    const float* __restrict__ out_w, const float* __restrict__ out_b,
    unsigned* __restrict__ Vg4,
    float* __restrict__ out, float* __restrict__ hT)
{
    // LDS: [0, 131072) AB params | V2s 256 ushorts (512 B) | xs2 [2][64] words (512 B)
    __shared__ __align__(16) unsigned char L[132096];
    unsigned short* V2s = (unsigned short*)(L + 131072);
    unsigned* xs2 = (unsigned*)(L + 131584);

    const int bx  = blockIdx.x;
    const int b   = bx & 127;
    const int jh  = bx >> 7;
    const int tid = threadIdx.x;
    const int c   = tid & 7;
    const int j   = tid >> 3;
    const int jg  = (jh << 7) + j;
    const int wv  = tid >> 6;            // wave id 0..15
    const int Ln  = tid & 63;            // lane in wave
    const int pjbase = (jh ^ 1) << 7;
    const int BH  = B_ * H_;

    // stage internal AB (own column-half, pre-swizzled) into LDS: 128 KB
    {
        const uint4* src = (const uint4*)(ABg + ((size_t)jh << 14));
        uint4* dst = (uint4*)L;
        #pragma unroll
        for (int k = 0; k < 8; ++k) dst[tid + (k << 10)] = src[tid + (k << 10)];
    }

    // internal W registers: 8 own + 8 peer pairs
    unsigned rw[16];
    {
        const int po = (jh << 6) + (c << 3);
        const int pp = ((jh ^ 1) << 6) + (c << 3);
        #pragma unroll
        for (int k = 0; k < 8; ++k) {
            rw[k]     = Wg[((po + k) << 8) + jg];
            rw[8 + k] = Wg[((pp + k) << 8) + jg];
        }
    }

    const float cmt  = cm[jg] * (float)UF;
    const float gl   = gleak[jg];
    const float glvl = gl * vleak[jg];
    const float dc   = cmt + gl + EPSF;
    const float owj  = out_w[jg], obj = out_b[jg];
    float iw0 = 0.f, iw1 = 0.f, ib0 = 0.f, ib1 = 0.f;
    if (tid < 64) { iw0 = in_w[2 * tid]; iw1 = in_w[2 * tid + 1];
                    ib0 = in_b[2 * tid]; ib1 = in_b[2 * tid + 1]; }
    if (tid < 128) ((unsigned*)V2s)[tid] = 0u;
    float vreg = 0.f;

    const float* xrow = x + (size_t)b * (T_ * I_);

    const int colb = (j ^ (c << 1)) << 3;   // swizzled column byte offset
    const char* abA = (const char*)L + ((((jh << 6) + (c << 3))) << 10) + colb;
    const char* abB = (const char*)L + (((((jh ^ 1) << 6)) + (c << 3)) << 10) + colb;
    const int vbaseA = (jh << 6) + (c << 3);
    const int vbaseB = ((jh ^ 1) << 6) + (c << 3);
    const unsigned* V2w = (const unsigned*)V2s;   // word view (packed pairs)
    const uint2* sabBase = SABg + ((c << 3) << 8) + jg;
    const unsigned* swBase = SWg + ((c << 3) << 8) + jg;

    // ---- prologue: xs2[0] + serial sensing for t=0
    if (tid < 64) {
        float2 xv = *(const float2*)(xrow + 2 * tid);
        H2U u_; u_.h = __floats2half2_rn(fmaf(xv.x, iw0, ib0), fmaf(xv.y, iw1, ib1));
        xs2[tid] = u_.u;
    }
    __syncthreads();
    float qsn = 0.f, qsd = 0.f;
    {
        const uint4 xa = *(const uint4*)(xs2 + (c << 3));
        const uint4 xb = *(const uint4*)(xs2 + (c << 3) + 4);
        #pragma unroll
        for (int k = 0; k < 8; ++k) {
            uint2 sab = sabBase[k << 8];
            unsigned swv = swBase[k << 8];
            unsigned xw = (k < 4) ? ((const unsigned*)&xa)[k] : ((const unsigned*)&xb)[k - 4];
            GATE2(xw, sab.x, sab.y, swv, qsn, qsd);
        }
    }

    for (int t = 0; t < T_; ++t) {
        const bool hasNext = (t + 1 < T_);
        unsigned* xsNxt = xs2 + (((t + 1) & 1) << 6);
        if (hasNext && tid < 64) {
            float2 xv = *(const float2*)(xrow + (t + 1) * I_ + 2 * tid);
            H2U u_; u_.h = __floats2half2_rn(fmaf(xv.x, iw0, ib0), fmaf(xv.y, iw1, ib1));
            xsNxt[tid] = u_.u;   // read by others only after unfold-0's barrier-a
        }
        float qn2 = 0.f, qd2 = 0.f;

        #pragma unroll
        for (int u = 0; u < UF; ++u) {
            const int p = t * UF + u + 1;
            float nm = qsn, dn = qsd;

            // ---- prefetch peer tagged word: lanes 0-7 of every wave, 1 word each
            unsigned pv = 0; unsigned want = 0;
            const unsigned* srcp = nullptr;
            const bool mine = (Ln < 8);
            if (p > 1) {
                want = (unsigned)(p - 1);
                srcp = Vg4 + (size_t)(want & 1) * BH + (b << 8) + pjbase + (wv << 3) + (Ln & 7);
                if (mine) pv = __hip_atomic_load(srcp, __ATOMIC_RELAXED, __HIP_MEMORY_SCOPE_AGENT);
            }

            // ---- sensing-next params: issue loads now, consume after barrier-a
            uint2 sp0 = make_uint2(0u, 0u), sp1 = make_uint2(0u, 0u);
            unsigned sv0 = 0, sv1 = 0;
            if (hasNext) {
                sp0 = sabBase[u << 8]; sv0 = swBase[u << 8];
                if (u >= 4) { sp1 = sabBase[(u + 2) << 8]; sv1 = swBase[(u + 2) << 8]; }
            }

            // ---- phase A: own-half source pairs (AB from LDS)
            {
                const uint4 va = *(const uint4*)(V2w + vbaseA);
                const uint4 vb = *(const uint4*)(V2w + vbaseA + 4);
                #pragma unroll
                for (int k = 0; k < 8; ++k) {
                    uint2 ab = *(const uint2*)(abA + (k << 10));
                    unsigned vw = (k < 4) ? ((const unsigned*)&va)[k] : ((const unsigned*)&vb)[k - 4];
                    GATE2(vw, ab.x, ab.y, rw[k], nm, dn);
                }
            }

            // ---- finish poll (all waves, 8 active lanes each), write peer V2s
            if (p > 1) {
                while (1) {
                    bool ok = !mine || ((pv >> 16) == want);
                    if (__all((int)ok)) break;
                    if (mine) pv = __hip_atomic_load(srcp, __ATOMIC_RELAXED, __HIP_MEMORY_SCOPE_AGENT);
                }
                if (mine) V2s[pjbase + (wv << 3) + (Ln & 7)] = (unsigned short)(pv & 0xffffu);
            }
            __syncthreads();   // barrier-a: peer V2s ready (and xsNxt at u==0)

            // ---- pipelined sensing for t+1 (xw ordered by barrier-a)
            if (hasNext) {
                unsigned xw0 = xsNxt[(c << 3) + u];
                GATE2(xw0, sp0.x, sp0.y, sv0, qn2, qd2);
                if (u >= 4) {
                    unsigned xw1 = xsNxt[(c << 3) + u + 2];
                    GATE2(xw1, sp1.x, sp1.y, sv1, qn2, qd2);
                }
            }

            // ---- phase B: peer-half source pairs
            {
                const uint4 va = *(const uint4*)(V2w + vbaseB);
                const uint4 vb = *(const uint4*)(V2w + vbaseB + 4);
                #pragma unroll
                for (int k = 0; k < 8; ++k) {
                    uint2 ab = *(const uint2*)(abB + (k << 10));
                    unsigned vw = (k < 4) ? ((const unsigned*)&va)[k] : ((const unsigned*)&vb)[k - 4];
                    GATE2(vw, ab.x, ab.y, rw[8 + k], nm, dn);
                }
            }

            // ---- in-wave reduce over c
            nm += __shfl_xor(nm, 1); dn += __shfl_xor(dn, 1);
            nm += __shfl_xor(nm, 2); dn += __shfl_xor(dn, 2);
            nm += __shfl_xor(nm, 4); dn += __shfl_xor(dn, 4);

            // ---- update (all lanes), publish tagged word + own V2s write (c==0)
            float Vn = (fmaf(vreg, cmt, glvl) + nm) * rcpf(dn + dc);
            vreg = Vn;
            unsigned h0 = (unsigned)__half_as_ushort(__float2half_rn(Vn));
            if (c == 0) {
                __hip_atomic_store(Vg4 + (size_t)(p & 1) * BH + (b << 8) + jg,
                                   ((unsigned)p << 16) | h0,
                                   __ATOMIC_RELAXED, __HIP_MEMORY_SCOPE_AGENT);
                V2s[jg] = (unsigned short)h0;
            }
            __syncthreads();   // barrier-b: own V2s ready for next phase A
        }

        if (hasNext) { qsn = qn2; qsd = qd2; }
        if (c == 0) out[((size_t)b * T_ + t) * H_ + jg] = fmaf(vreg, owj, obj);
    }
    if (c == 0) hT[(b << 8) + jg] = vreg;
}

extern "C" void kernel_launch(void* const* d_in, const int* in_sizes, int n_in,
                              void* d_out, int out_size, void* d_ws, size_t ws_size,
                              hipStream_t stream) {
    const float* x     = (const float*)d_in[0];
    const float* in_w  = (const float*)d_in[1];
    const float* in_b  = (const float*)d_in[2];
    const float* smu   = (const float*)d_in[3];
    const float* ssig  = (const float*)d_in[4];
    const float* sw    = (const float*)d_in[5];
    const float* serev = (const float*)d_in[6];
    const float* imu   = (const float*)d_in[7];
    const float* isig  = (const float*)d_in[8];
    const float* iw    = (const float*)d_in[9];
    const float* ierev = (const float*)d_in[10];
    const float* vleak = (const float*)d_in[11];
    const float* gleak = (const float*)d_in[12];
    const float* cmv   = (const float*)d_in[13];
    const float* ow    = (const float*)d_in[14];
    const float* ob    = (const float*)d_in[15];

    float* out = (float*)d_out;                 // [B, T, H]
    float* hT  = out + (size_t)B_ * T_ * H_;    // [B, H]

    char* w = (char*)d_ws;
    uint2*    ABg  = (uint2*)(w);                    // 256 KB [jh][P][jcol] swizzled
    unsigned* Wg   = (unsigned*)(w + (256 << 10));   // 128 KB [P][jg]
    uint2*    SABg = (uint2*)(w + (384 << 10));      // 128 KB [p][jg]
    unsigned* SWg  = (unsigned*)(w + (512 << 10));   //  64 KB [p][jg]
    unsigned* Vg4  = (unsigned*)(w + (576 << 10));   // 256 KB [2][B][H] tag|fp16

    pack_params<<<dim3(128), dim3(256), 0, stream>>>(
        smu, ssig, sw, serev, imu, isig, iw, ierev, ABg, Wg, SABg, SWg, Vg4);

    ltc_rec<<<dim3(256), dim3(1024), 0, stream>>>(
        x, in_w, in_b, ABg, Wg, SABg, SWg, vleak, gleak, cmv, ow, ob,
        Vg4, out, hT);
}

// Round 14
// 972.382 us; speedup vs baseline: 1.4299x; 1.4299x over previous
//
#include <hip/hip_runtime.h>
#include <hip/hip_fp16.h>

#define B_ 128
#define T_ 64
#define I_ 128
#define H_ 256
#define UF 6
#define EPSF 1e-8f

typedef _Float16 f16x2 __attribute__((ext_vector_type(2)));
union H2U { __half2 h; f16x2 v; unsigned u; };

static __device__ __forceinline__ float rcpf(float x) { return __builtin_amdgcn_rcpf(x); }
static __device__ __forceinline__ unsigned f2h(float f) { return (unsigned)__half_as_ushort(__float2half_rn(f)); }

// packed-fp16 dual gate: 2 sigmoids + f32 dot-accumulate into NM/DN
#define GATE2(VW, AK, BK, WK, NM, DN) {                        \
    H2U v2_; v2_.u = (VW);                                     \
    H2U av_; av_.u = (AK);                                     \
    H2U bv_; bv_.u = (BK);                                     \
    __half2 z_ = __hfma2(av_.h, v2_.h, bv_.h);                 \
    __half2 e_ = h2exp2(z_);                                   \
    __half2 s_ = __hadd2(e_, __float2half2_rn(1.0f));          \
    H2U rv_; rv_.h = h2rcp(s_);                                \
    H2U ws_; ws_.u = (WK);                                     \
    H2U wa_; wa_.u = ws_.u & 0x7fff7fffu;                      \
    NM = __builtin_amdgcn_fdot2(ws_.v, rv_.v, NM, false);      \
    DN = __builtin_amdgcn_fdot2(wa_.v, rv_.v, DN, false);      \
}

// ---------------- K0: pack params (A = -sig*L2E, B = sig*mu*L2E, W = w*erev).
// Internal AB: bank-swizzled [jh][P][jcol] uint2, jcol = j ^ 2*((P>>3)&7).
// Internal W:  [P][jg] packed pairs. Sensing: SAB [p][jg] uint2, SW [p][jg].
// Zero the exchange tags (both buffers) every launch.
__global__ __launch_bounds__(256) void pack_params(
    const float* __restrict__ smu, const float* __restrict__ ssig,
    const float* __restrict__ sw,  const float* __restrict__ serev,
    const float* __restrict__ imu, const float* __restrict__ isig,
    const float* __restrict__ iw,  const float* __restrict__ ierev,
    uint2* __restrict__ ABg, unsigned* __restrict__ Wg,
    uint2* __restrict__ SABg, unsigned* __restrict__ SWg,
    unsigned* __restrict__ Vg4)
{
    const float K = 1.4426950408889634f;
    int idx = blockIdx.x * 256 + threadIdx.x;     // [0, 32768)
    {   // internal AB, swizzled columns
        int jh = idx >> 14, rest = idx & 16383;
        int P = rest >> 7, jcol = rest & 127;
        int j = jcol ^ (((P >> 3) & 7) << 1);
        int jg = (jh << 7) + j;
        int i0 = 2 * P, i1 = i0 + 1;
        unsigned a0 = f2h(-isig[i0 * H_ + jg] * K);
        unsigned a1 = f2h(-isig[i1 * H_ + jg] * K);
        unsigned b0 = f2h(isig[i0 * H_ + jg] * imu[i0 * H_ + jg] * K);
        unsigned b1 = f2h(isig[i1 * H_ + jg] * imu[i1 * H_ + jg] * K);
        ABg[idx] = make_uint2(a0 | (a1 << 16), b0 | (b1 << 16));
    }
    {   // internal W [P][jg]
        int P = idx >> 8, jg = idx & 255;
        int i0 = 2 * P, i1 = i0 + 1;
        unsigned w0 = f2h(iw[i0 * H_ + jg] * ierev[i0 * H_ + jg]);
        unsigned w1 = f2h(iw[i1 * H_ + jg] * ierev[i1 * H_ + jg]);
        Wg[idx] = w0 | (w1 << 16);
    }
    if (idx < 64 * H_) {   // sensing [p][jg]
        int p = idx >> 8, jg = idx & 255;
        int i0 = 2 * p, i1 = i0 + 1;
        unsigned a0 = f2h(-ssig[i0 * H_ + jg] * K);
        unsigned a1 = f2h(-ssig[i1 * H_ + jg] * K);
        unsigned b0 = f2h(ssig[i0 * H_ + jg] * smu[i0 * H_ + jg] * K);
        unsigned b1 = f2h(ssig[i1 * H_ + jg] * smu[i1 * H_ + jg] * K);
        SABg[idx] = make_uint2(a0 | (a1 << 16), b0 | (b1 << 16));
        unsigned w0 = f2h(sw[i0 * H_ + jg] * serev[i0 * H_ + jg]);
        unsigned w1 = f2h(sw[i1 * H_ + jg] * serev[i1 * H_ + jg]);
        SWg[idx] = w0 | (w1 << 16);
    }
    Vg4[idx] = 0u;
    Vg4[idx + 32768] = 0u;
}

// ---------------- K1: recurrent LTC (R7 structure — proven best, 972 us).
// 2 blocks per batch (j-half each), 1 block/CU (131 KB LDS), all 256 co-resident.
// Lane map tid = j*8 + c; 8 partials per neuron reduce via shfl_xor in-wave.
// Internal A,B in LDS (XOR-swizzled, ds_read_b64); internal W register-cached
// (16 words, fits 64-VGPR alloc, no remat); sensing params streamed from L2
// once per t (amortized over 6 unfolds). Cross-block V via self-tagged relaxed
// agent atomics (tag<<16 | fp16(V)), double-buffered by unfold parity; waves
// 0-1 poll (1 word/lane), prefetch issued before phase A so the L2 RT hides
// under gate compute. 2 barriers per unfold.
__global__ __launch_bounds__(1024)
__attribute__((amdgpu_waves_per_eu(4, 4)))
void ltc_rec(
    const float* __restrict__ x, const float* __restrict__ in_w, const float* __restrict__ in_b,
    const uint2* __restrict__ ABg, const unsigned* __restrict__ Wg,
    const uint2* __restrict__ SABg, const unsigned* __restrict__ SWg,
    const float* __restrict__ vleak, const float* __restrict__ gleak, const float* __restrict__ cm,
    const float* __restrict__ out_w, const float* __restrict__ out_b,
    unsigned* __restrict__ Vg4,
    float* __restrict__ out, float* __restrict__ hT)
{
    // LDS: [0, 131072) AB params | V2u (512 B) | xs2 (256 B)
    __shared__ __align__(16) unsigned char L[131840];
    unsigned* V2u = (unsigned*)(L + 131072);
    unsigned* xs2 = (unsigned*)(L + 131584);

    const int bx  = blockIdx.x;
    const int b   = bx & 127;
    const int jh  = bx >> 7;
    const int tid = threadIdx.x;
    const int c   = tid & 7;
    const int j   = tid >> 3;
    const int jg  = (jh << 7) + j;
    const int pjbase = (jh ^ 1) << 7;
    const int BH  = B_ * H_;

    // stage internal AB (own column-half, pre-swizzled) into LDS: 128 KB
    {
        const uint4* src = (const uint4*)(ABg + ((size_t)jh << 14));
        uint4* dst = (uint4*)L;
        #pragma unroll
        for (int k = 0; k < 8; ++k) dst[tid + (k << 10)] = src[tid + (k << 10)];
    }

    // internal W registers: 8 own + 8 peer pairs
    unsigned rw[16];
    {
        const int po = (jh << 6) + (c << 3);
        const int pp = ((jh ^ 1) << 6) + (c << 3);
        #pragma unroll
        for (int k = 0; k < 8; ++k) {
            rw[k]     = Wg[((po + k) << 8) + jg];
            rw[8 + k] = Wg[((pp + k) << 8) + jg];
        }
    }

    const float cmt  = cm[jg] * (float)UF;
    const float gl   = gleak[jg];
    const float glvl = gl * vleak[jg];
    const float dc   = cmt + gl + EPSF;
    const float owj  = out_w[jg], obj = out_b[jg];
    float iw0 = 0.f, iw1 = 0.f, ib0 = 0.f, ib1 = 0.f;
    if (tid < 64) { iw0 = in_w[2 * tid]; iw1 = in_w[2 * tid + 1];
                    ib0 = in_b[2 * tid]; ib1 = in_b[2 * tid + 1]; }
    if (tid < 128) V2u[tid] = 0u;
    float vreg = 0.f;

    const float* xrow = x + (size_t)b * (T_ * I_);

    const int colb = (j ^ (c << 1)) << 3;   // swizzled column byte offset
    const char* abA = (const char*)L + ((((jh << 6) + (c << 3))) << 10) + colb;
    const char* abB = (const char*)L + (((((jh ^ 1) << 6)) + (c << 3)) << 10) + colb;
    const int vbaseA = (jh << 6) + (c << 3);
    const int vbaseB = ((jh ^ 1) << 6) + (c << 3);
    const uint2* sabBase = SABg + ((c << 3) << 8) + jg;
    const unsigned* swBase = SWg + ((c << 3) << 8) + jg;

    for (int t = 0; t < T_; ++t) {
        if (tid < 64) {
            float2 xv = *(const float2*)(xrow + t * I_ + 2 * tid);
            H2U u_; u_.h = __floats2half2_rn(fmaf(xv.x, iw0, ib0), fmaf(xv.y, iw1, ib1));
            xs2[tid] = u_.u;
        }
        __syncthreads();   // xs2 ready (covers AB/V2u init at t==0)

        // ---- sensing partials: params streamed from L2, reused for 6 unfolds
        float qsn = 0.f, qsd = 0.f;
        {
            const uint4 xa = *(const uint4*)(xs2 + (c << 3));
            const uint4 xb = *(const uint4*)(xs2 + (c << 3) + 4);
            #pragma unroll
            for (int k = 0; k < 8; ++k) {
                uint2 sab = sabBase[k << 8];
                unsigned swv = swBase[k << 8];
                unsigned xw = (k < 4) ? ((const unsigned*)&xa)[k] : ((const unsigned*)&xb)[k - 4];
                GATE2(xw, sab.x, sab.y, swv, qsn, qsd);
            }
        }

        for (int u = 0; u < UF; ++u) {
            const int p = t * UF + u + 1;
            float nm = qsn, dn = qsd;

            // prefetch peer V(p-1): issue load now, check after phase A
            unsigned pv = 0; const unsigned* src = nullptr; unsigned want = 0;
            if (p > 1 && tid < 128) {
                want = (unsigned)(p - 1);
                src = Vg4 + (size_t)(want & 1) * BH + (b << 8) + pjbase + tid;
                pv = __hip_atomic_load(src, __ATOMIC_RELAXED, __HIP_MEMORY_SCOPE_AGENT);
            }

            // ---- phase A: own-half source pairs (AB from LDS)
            {
                const uint4 va = *(const uint4*)(V2u + vbaseA);
                const uint4 vb = *(const uint4*)(V2u + vbaseA + 4);
                #pragma unroll
                for (int k = 0; k < 8; ++k) {
                    uint2 ab = *(const uint2*)(abA + (k << 10));
                    unsigned vw = (k < 4) ? ((const unsigned*)&va)[k] : ((const unsigned*)&vb)[k - 4];
                    GATE2(vw, ab.x, ab.y, rw[k], nm, dn);
                }
            }

            // ---- waves 0-1: finish poll, write peer V2u region
            if (p > 1 && tid < 128) {
                while ((pv >> 16) != want)
                    pv = __hip_atomic_load(src, __ATOMIC_RELAXED, __HIP_MEMORY_SCOPE_AGENT);
                unsigned hv = pv & 0xffffu;
                unsigned hv1 = (unsigned)__shfl_down((int)hv, 1);
                if (!(tid & 1)) V2u[(pjbase >> 1) + (tid >> 1)] = hv | (hv1 << 16);
            }
            __syncthreads();   // peer V2u ready

            // ---- phase B: peer-half source pairs
            {
                const uint4 va = *(const uint4*)(V2u + vbaseB);
                const uint4 vb = *(const uint4*)(V2u + vbaseB + 4);
                #pragma unroll
                for (int k = 0; k < 8; ++k) {
                    uint2 ab = *(const uint2*)(abB + (k << 10));
                    unsigned vw = (k < 4) ? ((const unsigned*)&va)[k] : ((const unsigned*)&vb)[k - 4];
                    GATE2(vw, ab.x, ab.y, rw[8 + k], nm, dn);
                }
            }

            // ---- in-wave reduce over c
            nm += __shfl_xor(nm, 1); dn += __shfl_xor(dn, 1);
            nm += __shfl_xor(nm, 2); dn += __shfl_xor(dn, 2);
            nm += __shfl_xor(nm, 4); dn += __shfl_xor(dn, 4);

            // ---- update (all lanes), publish + own V2u write
            float Vn = (fmaf(vreg, cmt, glvl) + nm) * rcpf(dn + dc);
            vreg = Vn;
            unsigned h0 = (unsigned)__half_as_ushort(__float2half_rn(Vn));
            if (c == 0)
                __hip_atomic_store(Vg4 + (size_t)(p & 1) * BH + (b << 8) + jg,
                                   ((unsigned)p << 16) | h0,
                                   __ATOMIC_RELAXED, __HIP_MEMORY_SCOPE_AGENT);
            unsigned h1 = (unsigned)__shfl_down((int)h0, 8);
            if (c == 0 && !(j & 1)) V2u[jg >> 1] = h0 | (h1 << 16);
            __syncthreads();   // own V2u ready for next phase A
        }

        if (c == 0) out[((size_t)b * T_ + t) * H_ + jg] = fmaf(vreg, owj, obj);
    }
    if (c == 0) hT[(b << 8) + jg] = vreg;
}

extern "C" void kernel_launch(void* const* d_in, const int* in_sizes, int n_in,
                              void* d_out, int out_size, void* d_ws, size_t ws_size,
                              hipStream_t stream) {
    const float* x     = (const float*)d_in[0];
    const float* in_w  = (const float*)d_in[1];
    const float* in_b  = (const float*)d_in[2];
    const float* smu   = (const float*)d_in[3];
    const float* ssig  = (const float*)d_in[4];
    const float* sw    = (const float*)d_in[5];
    const float* serev = (const float*)d_in[6];
    const float* imu   = (const float*)d_in[7];
    const float* isig  = (const float*)d_in[8];
    const float* iw    = (const float*)d_in[9];
    const float* ierev = (const float*)d_in[10];
    const float* vleak = (const float*)d_in[11];
    const float* gleak = (const float*)d_in[12];
    const float* cmv   = (const float*)d_in[13];
    const float* ow    = (const float*)d_in[14];
    const float* ob    = (const float*)d_in[15];

    float* out = (float*)d_out;                 // [B, T, H]
    float* hT  = out + (size_t)B_ * T_ * H_;    // [B, H]

    char* w = (char*)d_ws;
    uint2*    ABg  = (uint2*)(w);                    // 256 KB [jh][P][jcol] swizzled
    unsigned* Wg   = (unsigned*)(w + (256 << 10));   // 128 KB [P][jg]
    uint2*    SABg = (uint2*)(w + (384 << 10));      // 128 KB [p][jg]
    unsigned* SWg  = (unsigned*)(w + (512 << 10));   //  64 KB [p][jg]
    unsigned* Vg4  = (unsigned*)(w + (576 << 10));   // 256 KB [2][B][H] tag|fp16

    pack_params<<<dim3(128), dim3(256), 0, stream>>>(
        smu, ssig, sw, serev, imu, isig, iw, ierev, ABg, Wg, SABg, SWg, Vg4);

    ltc_rec<<<dim3(256), dim3(1024), 0, stream>>>(
        x, in_w, in_b, ABg, Wg, SABg, SWg, vleak, gleak, cmv, ow, ob,
        Vg4, out, hT);
}